// Round 6
// baseline (110.865 us; speedup 1.0000x reference)
//
#include <hip/hip_runtime.h>

#define NQ 4
#define NL 2
#define NA 16
#define HDIM 256
#define RPB 256   // rows per block; 256 threads; B=262144 -> 1024 blocks

template<int PATTERN>
__device__ __forceinline__ float swz_add(float x) {
    return x + __int_as_float(__builtin_amdgcn_ds_swizzle(__float_as_int(x), PATTERN));
}

__device__ __forceinline__ float dot4(float4 a, float4 b) {
    return fmaf(a.x, b.x, fmaf(a.y, b.y, fmaf(a.z, b.z, a.w * b.w)));
}

// 1-qubit gate, qubit mask M. u0={u00r,u00i,u01r,u01i}, u1={u10r,u10i,u11r,u11i}
template<int M>
__device__ __forceinline__ void apply_u(float* sr, float* si, const float4 u0, const float4 u1) {
#pragma unroll
    for (int k = 0; k < 16; ++k) {
        if (k & M) continue;
        const int k1 = k | M;
        const float a0r = sr[k],  a0i = si[k];
        const float a1r = sr[k1], a1i = si[k1];
        sr[k]  = u0.x*a0r - u0.y*a0i + u0.z*a1r - u0.w*a1i;
        si[k]  = u0.x*a0i + u0.y*a0r + u0.z*a1i + u0.w*a1r;
        sr[k1] = u1.x*a0r - u1.y*a0i + u1.z*a1r - u1.w*a1i;
        si[k1] = u1.x*a0i + u1.y*a0r + u1.z*a1i + u1.w*a1r;
    }
}

template<int MC, int MT>
__device__ __forceinline__ void cnot(float* sr, float* si) {
#pragma unroll
    for (int k = 0; k < 16; ++k) {
        if ((k & MC) && !(k & MT)) {
            const int k1 = k | MT;
            float tr = sr[k]; sr[k] = sr[k1]; sr[k1] = tr;
            float ti = si[k]; si[k] = si[k1]; si[k1] = ti;
        }
    }
}

__global__ __launch_bounds__(256, 4) void qph_kernel(
    const float* __restrict__ h,
    const float* __restrict__ W_embed,
    const float* __restrict__ b_embed,
    const float* __restrict__ q_weights,
    const float* __restrict__ W_out,
    const float* __restrict__ b_out,
    float* __restrict__ out,
    int B)
{
    __shared__ __align__(16) float rot_lds[NL * NQ][8];   // 8 Rot matrices
    __shared__ __align__(16) float wout_lds[NA * NQ];
    __shared__ float bout_lds[NA];
    __shared__ __align__(16) float zbuf[RPB][4];          // 4 KB z handoff

    const int tid = threadIdx.x;
    const int l16 = tid & 15;   // lane within 16-lane row-group
    const int g   = tid >> 4;   // group id 0..15
    const long rowBase = (long)blockIdx.x * RPB;

    // ---- stage tiny shared data ----
    if (tid < NA * NQ) wout_lds[tid] = W_out[tid];
    if (tid < NA)      bout_lds[tid] = b_out[tid];
    if (tid < NL * NQ) {
        // Rot(phi,theta,omega) = RZ(omega) RY(theta) RZ(phi)
        const float phi = q_weights[tid * 3 + 0];
        const float th  = q_weights[tid * 3 + 1];
        const float om  = q_weights[tid * 3 + 2];
        const float c  = cosf(0.5f * th), s  = sinf(0.5f * th);
        const float al = 0.5f * (phi + om), be = 0.5f * (phi - om);
        const float ca = cosf(al), sa = sinf(al);
        const float cb = cosf(be), sb = sinf(be);
        rot_lds[tid][0] =  ca * c;  rot_lds[tid][1] = -sa * c;   // u00
        rot_lds[tid][2] = -cb * s;  rot_lds[tid][3] = -sb * s;   // u01
        rot_lds[tid][4] =  cb * s;  rot_lds[tid][5] = -sb * s;   // u10
        rot_lds[tid][6] =  ca * c;  rot_lds[tid][7] =  sa * c;   // u11
    }
    __syncthreads();

    // ---- W_embed into registers: lane l16 owns cols {s*64 + l16*4 .. +3}, s=0..3 ----
    float4 wreg[4][4];
#pragma unroll
    for (int q = 0; q < 4; ++q)
#pragma unroll
        for (int s = 0; s < 4; ++s)
            wreg[q][s] = *(const float4*)(W_embed + q * HDIM + s * 64 + l16 * 4);
    const float be0 = b_embed[0], be1 = b_embed[1], be2 = b_embed[2], be3 = b_embed[3];

    // ---- phase 1: 16 iterations, one row per 16-lane group per iteration ----
    // After the 4-step ds_swizzle butterfly every lane holds the row's 4 sums;
    // lane l16 keeps iteration l16's row -> every thread owns exactly one row.
    float my0 = 0.f, my1 = 0.f, my2 = 0.f, my3 = 0.f;

#pragma unroll
    for (int it = 0; it < 16; ++it) {
        const long r = rowBase + it * 16 + g;
        float4 hv0 = make_float4(0,0,0,0), hv1 = hv0, hv2 = hv0, hv3 = hv0;
        if (r < B) {
            const float4* hrow = (const float4*)(h + r * (long)HDIM);
            hv0 = hrow[0 * 16 + l16];
            hv1 = hrow[1 * 16 + l16];
            hv2 = hrow[2 * 16 + l16];
            hv3 = hrow[3 * 16 + l16];
        }
        float a[4];
#pragma unroll
        for (int q = 0; q < 4; ++q) {
            a[q] = dot4(hv0, wreg[q][0]) + dot4(hv1, wreg[q][1])
                 + dot4(hv2, wreg[q][2]) + dot4(hv3, wreg[q][3]);
        }
        // 16-lane butterfly (xor 1,2,4,8), single-instruction ds_swizzle each
#pragma unroll
        for (int q = 0; q < 4; ++q) {
            a[q] = swz_add<0x041F>(a[q]);
            a[q] = swz_add<0x081F>(a[q]);
            a[q] = swz_add<0x101F>(a[q]);
            a[q] = swz_add<0x201F>(a[q]);
        }
        if (l16 == it) { my0 = a[0]; my1 = a[1]; my2 = a[2]; my3 = a[3]; }
    }

    // ---- phase 2: this thread owns row rowBase + l16*16 + g ----
    const int  lrow = l16 * 16 + g;            // bijective over [0,256)
    const long grow = rowBase + lrow;

    if (grow < B) {
        const float angs[4] = {tanhf(my0 + be0), tanhf(my1 + be1),
                               tanhf(my2 + be2), tanhf(my3 + be3)};

        float sr[16], si[16];
#pragma unroll
        for (int k = 0; k < 16; ++k) { sr[k] = 0.f; si[k] = 0.f; }
        sr[0] = 1.0f;

        // AngleEmbedding: RX(theta_q)
#pragma unroll
        for (int q = 0; q < NQ; ++q) {
            const float th = angs[q];
            const float c = __cosf(0.5f * th), s = __sinf(0.5f * th);
            const int m = 8 >> q;
#pragma unroll
            for (int k = 0; k < 16; ++k) {
                if (k & m) continue;
                const int k1 = k | m;
                const float a0r = sr[k],  a0i = si[k];
                const float a1r = sr[k1], a1i = si[k1];
                sr[k]  = c * a0r + s * a1i;
                si[k]  = c * a0i - s * a1r;
                sr[k1] = s * a0i + c * a1r;
                si[k1] = c * a1i - s * a0r;
            }
        }

        // StronglyEntanglingLayers (rot matrices broadcast from LDS as float4 pairs)
#pragma unroll
        for (int w = 0; w < 4; ++w) {
            const float4 u0 = *(const float4*)&rot_lds[w][0];
            const float4 u1 = *(const float4*)&rot_lds[w][4];
            if (w == 0) apply_u<8>(sr, si, u0, u1);
            if (w == 1) apply_u<4>(sr, si, u0, u1);
            if (w == 2) apply_u<2>(sr, si, u0, u1);
            if (w == 3) apply_u<1>(sr, si, u0, u1);
        }
        cnot<8, 4>(sr, si);
        cnot<4, 2>(sr, si);
        cnot<2, 1>(sr, si);
        cnot<1, 8>(sr, si);
#pragma unroll
        for (int w = 0; w < 4; ++w) {
            const float4 u0 = *(const float4*)&rot_lds[4 + w][0];
            const float4 u1 = *(const float4*)&rot_lds[4 + w][4];
            if (w == 0) apply_u<8>(sr, si, u0, u1);
            if (w == 1) apply_u<4>(sr, si, u0, u1);
            if (w == 2) apply_u<2>(sr, si, u0, u1);
            if (w == 3) apply_u<1>(sr, si, u0, u1);
        }
        cnot<8, 2>(sr, si);
        cnot<4, 1>(sr, si);
        cnot<2, 8>(sr, si);
        cnot<1, 4>(sr, si);

        // PauliZ expectations
        float p[16];
#pragma unroll
        for (int k = 0; k < 16; ++k) p[k] = sr[k] * sr[k] + si[k] * si[k];
        float4 z;
        {
            float zt[4];
#pragma unroll
            for (int q = 0; q < NQ; ++q) {
                const int m = 8 >> q;
                float zz = 0.f;
#pragma unroll
                for (int k = 0; k < 16; ++k) zz += (k & m) ? -p[k] : p[k];
                zt[q] = zz;
            }
            z = make_float4(zt[0], zt[1], zt[2], zt[3]);
        }
        *(float4*)&zbuf[lrow][0] = z;
    }
    __syncthreads();

    // ---- phase 3: coalesced output. thread tid -> row rowBase + tid ----
    const long orow = rowBase + tid;
    if (orow >= B) return;
    const float4 zv = *(const float4*)&zbuf[tid][0];

    float4* out4 = (float4*)(out + orow * (long)NA);
#pragma unroll
    for (int i = 0; i < 4; ++i) {
        float o[4];
#pragma unroll
        for (int jj = 0; jj < 4; ++jj) {
            const int a = i * 4 + jj;
            const float4 w = *(const float4*)&wout_lds[a * 4];
            o[jj] = bout_lds[a] + zv.x * w.x + zv.y * w.y + zv.z * w.z + zv.w * w.w;
        }
        out4[i] = make_float4(o[0], o[1], o[2], o[3]);
    }
}

extern "C" void kernel_launch(void* const* d_in, const int* in_sizes, int n_in,
                              void* d_out, int out_size, void* d_ws, size_t ws_size,
                              hipStream_t stream) {
    const float* h         = (const float*)d_in[0];
    const float* W_embed   = (const float*)d_in[1];
    const float* b_embed   = (const float*)d_in[2];
    const float* q_weights = (const float*)d_in[3];
    const float* W_out     = (const float*)d_in[4];
    const float* b_out     = (const float*)d_in[5];
    float* out = (float*)d_out;

    const int B = in_sizes[0] / HDIM;
    const int blocks = (B + RPB - 1) / RPB;
    qph_kernel<<<blocks, 256, 0, stream>>>(h, W_embed, b_embed, q_weights, W_out, b_out, out, B);
}

// Round 7
// 57.770 us; speedup vs baseline: 1.9191x; 1.9191x over previous
//
#include <hip/hip_runtime.h>

#define NQ 4
#define NL 2
#define NA 16
#define HDIM 256
#define BLK 64    // threads per block = 1 wave
#define RPB 64    // rows per block -> 4096 blocks at B=262144

// Generic 1-qubit gate on qubit with mask M. u = {u00r,u00i,u01r,u01i,u10r,u10i,u11r,u11i}
template<int M>
__device__ __forceinline__ void apply_u(float* sr, float* si, const float* u) {
    const float u00r = u[0], u00i = u[1], u01r = u[2], u01i = u[3];
    const float u10r = u[4], u10i = u[5], u11r = u[6], u11i = u[7];
#pragma unroll
    for (int k = 0; k < 16; ++k) {
        if (k & M) continue;
        const int k1 = k | M;
        const float a0r = sr[k],  a0i = si[k];
        const float a1r = sr[k1], a1i = si[k1];
        sr[k]  = u00r*a0r - u00i*a0i + u01r*a1r - u01i*a1i;
        si[k]  = u00r*a0i + u00i*a0r + u01r*a1i + u01i*a1r;
        sr[k1] = u10r*a0r - u10i*a0i + u11r*a1r - u11i*a1i;
        si[k1] = u10r*a0i + u10i*a0r + u11r*a1i + u11i*a1r;
    }
}

template<int MC, int MT>
__device__ __forceinline__ void cnot(float* sr, float* si) {
#pragma unroll
    for (int k = 0; k < 16; ++k) {
        if ((k & MC) && !(k & MT)) {
            const int k1 = k | MT;
            float tr = sr[k]; sr[k] = sr[k1]; sr[k1] = tr;
            float ti = si[k]; si[k] = si[k1]; si[k1] = ti;
        }
    }
}

__global__ __launch_bounds__(BLK) void qph_kernel(
    const float* __restrict__ h,
    const float* __restrict__ W_embed,
    const float* __restrict__ b_embed,
    const float* __restrict__ q_weights,
    const float* __restrict__ W_out,
    const float* __restrict__ b_out,
    float* __restrict__ out,
    int B)
{
    __shared__ __align__(16) float w_lds[NQ * HDIM];   // 4 KB  W_embed
    __shared__ float rot_lds[NL * NQ][8];              // Rot matrices (shared across batch)
    __shared__ float wout_lds[NA * NQ];
    __shared__ float bout_lds[NA];

    const int tid = threadIdx.x;
    const long rowBase = (long)blockIdx.x * RPB;

    // ---- stage shared weights (single wave: barrier only formal) ----
#pragma unroll
    for (int k = 0; k < 16; ++k) w_lds[tid + k * BLK] = W_embed[tid + k * BLK];
    if (tid < NA * NQ) wout_lds[tid] = W_out[tid];
    if (tid < NA)      bout_lds[tid] = b_out[tid];
    if (tid < NL * NQ) {
        // Rot(phi,theta,omega) = RZ(omega) RY(theta) RZ(phi)
        const float phi = q_weights[tid * 3 + 0];
        const float th  = q_weights[tid * 3 + 1];
        const float om  = q_weights[tid * 3 + 2];
        const float c  = cosf(0.5f * th), s  = sinf(0.5f * th);
        const float al = 0.5f * (phi + om), be = 0.5f * (phi - om);
        const float ca = cosf(al), sa = sinf(al);
        const float cb = cosf(be), sb = sinf(be);
        rot_lds[tid][0] =  ca * c;  rot_lds[tid][1] = -sa * c;   // u00
        rot_lds[tid][2] = -cb * s;  rot_lds[tid][3] = -sb * s;   // u01
        rot_lds[tid][4] =  cb * s;  rot_lds[tid][5] = -sb * s;   // u10
        rot_lds[tid][6] =  ca * c;  rot_lds[tid][7] =  sa * c;   // u11
    }
    __syncthreads();

    // ---- phase 1: angles = tanh(h @ W_embed^T + b_embed), 4 lanes per row ----
    // After the 4-lane butterfly every lane holds all 4 sums; lane t keeps
    // iteration rr==t, so thread tid ends owning row rowBase+tid.
    const int t = tid & 3;   // lane within 4-lane group
    const int g = tid >> 2;  // group id 0..15
    const float be0 = b_embed[0], be1 = b_embed[1], be2 = b_embed[2], be3 = b_embed[3];

    float my0 = 0.f, my1 = 0.f, my2 = 0.f, my3 = 0.f;

#pragma unroll
    for (int rr = 0; rr < 4; ++rr) {
        const int  lrow = g * 4 + rr;
        const long grow = rowBase + lrow;
        float acc0 = 0.f, acc1 = 0.f, acc2 = 0.f, acc3 = 0.f;
        if (grow < B) {
            const float4* hrow = (const float4*)(h + grow * (long)HDIM);
#pragma unroll
            for (int j = 0; j < 16; ++j) {
                const float4 hv = hrow[j * 4 + t];
                const float4 w0 = *(const float4*)&w_lds[0 * HDIM + j * 16 + t * 4];
                const float4 w1 = *(const float4*)&w_lds[1 * HDIM + j * 16 + t * 4];
                const float4 w2 = *(const float4*)&w_lds[2 * HDIM + j * 16 + t * 4];
                const float4 w3 = *(const float4*)&w_lds[3 * HDIM + j * 16 + t * 4];
                acc0 = fmaf(hv.x, w0.x, fmaf(hv.y, w0.y, fmaf(hv.z, w0.z, fmaf(hv.w, w0.w, acc0))));
                acc1 = fmaf(hv.x, w1.x, fmaf(hv.y, w1.y, fmaf(hv.z, w1.z, fmaf(hv.w, w1.w, acc1))));
                acc2 = fmaf(hv.x, w2.x, fmaf(hv.y, w2.y, fmaf(hv.z, w2.z, fmaf(hv.w, w2.w, acc2))));
                acc3 = fmaf(hv.x, w3.x, fmaf(hv.y, w3.y, fmaf(hv.z, w3.z, fmaf(hv.w, w3.w, acc3))));
            }
        }
        // 4-lane butterfly -> all lanes hold the row's 4 sums
        acc0 += __shfl_xor(acc0, 1); acc0 += __shfl_xor(acc0, 2);
        acc1 += __shfl_xor(acc1, 1); acc1 += __shfl_xor(acc1, 2);
        acc2 += __shfl_xor(acc2, 1); acc2 += __shfl_xor(acc2, 2);
        acc3 += __shfl_xor(acc3, 1); acc3 += __shfl_xor(acc3, 2);
        if (t == rr) { my0 = acc0; my1 = acc1; my2 = acc2; my3 = acc3; }
    }

    // ---- phase 2: this thread owns row rowBase + tid ----
    const long grow = rowBase + tid;
    if (grow >= B) return;

    const float angs[4] = {tanhf(my0 + be0), tanhf(my1 + be1),
                           tanhf(my2 + be2), tanhf(my3 + be3)};

    float sr[16], si[16];
#pragma unroll
    for (int k = 0; k < 16; ++k) { sr[k] = 0.f; si[k] = 0.f; }
    sr[0] = 1.0f;

    // AngleEmbedding: RX(theta_q) on qubit q
#pragma unroll
    for (int q = 0; q < NQ; ++q) {
        const float th = angs[q];
        const float c = __cosf(0.5f * th), s = __sinf(0.5f * th);
        const int m = 8 >> q;
#pragma unroll
        for (int k = 0; k < 16; ++k) {
            if (k & m) continue;
            const int k1 = k | m;
            const float a0r = sr[k],  a0i = si[k];
            const float a1r = sr[k1], a1i = si[k1];
            sr[k]  = c * a0r + s * a1i;
            si[k]  = c * a0i - s * a1r;
            sr[k1] = s * a0i + c * a1r;
            si[k1] = c * a1i - s * a0r;
        }
    }

    // StronglyEntanglingLayers
    apply_u<8>(sr, si, rot_lds[0]);
    apply_u<4>(sr, si, rot_lds[1]);
    apply_u<2>(sr, si, rot_lds[2]);
    apply_u<1>(sr, si, rot_lds[3]);
    cnot<8, 4>(sr, si);
    cnot<4, 2>(sr, si);
    cnot<2, 1>(sr, si);
    cnot<1, 8>(sr, si);
    apply_u<8>(sr, si, rot_lds[4]);
    apply_u<4>(sr, si, rot_lds[5]);
    apply_u<2>(sr, si, rot_lds[6]);
    apply_u<1>(sr, si, rot_lds[7]);
    cnot<8, 2>(sr, si);
    cnot<4, 1>(sr, si);
    cnot<2, 8>(sr, si);
    cnot<1, 4>(sr, si);

    // PauliZ expectations
    float p[16];
#pragma unroll
    for (int k = 0; k < 16; ++k) p[k] = sr[k] * sr[k] + si[k] * si[k];
    float z[4];
#pragma unroll
    for (int q = 0; q < NQ; ++q) {
        const int m = 8 >> q;
        float zz = 0.f;
#pragma unroll
        for (int k = 0; k < 16; ++k) zz += (k & m) ? -p[k] : p[k];
        z[q] = zz;
    }

    // out = z @ W_out^T + b_out
    float4* out4 = (float4*)(out + grow * (long)NA);
#pragma unroll
    for (int i = 0; i < 4; ++i) {
        float o[4];
#pragma unroll
        for (int jj = 0; jj < 4; ++jj) {
            const int a = i * 4 + jj;
            float v = bout_lds[a];
#pragma unroll
            for (int q = 0; q < NQ; ++q) v = fmaf(z[q], wout_lds[a * 4 + q], v);
            o[jj] = v;
        }
        out4[i] = make_float4(o[0], o[1], o[2], o[3]);
    }
}

extern "C" void kernel_launch(void* const* d_in, const int* in_sizes, int n_in,
                              void* d_out, int out_size, void* d_ws, size_t ws_size,
                              hipStream_t stream) {
    const float* h         = (const float*)d_in[0];
    const float* W_embed   = (const float*)d_in[1];
    const float* b_embed   = (const float*)d_in[2];
    const float* q_weights = (const float*)d_in[3];
    const float* W_out     = (const float*)d_in[4];
    const float* b_out     = (const float*)d_in[5];
    float* out = (float*)d_out;

    const int B = in_sizes[0] / HDIM;
    const int blocks = (B + RPB - 1) / RPB;
    qph_kernel<<<blocks, BLK, 0, stream>>>(h, W_embed, b_embed, q_weights, W_out, b_out, out, B);
}

// Round 8
// 54.222 us; speedup vs baseline: 2.0447x; 1.0654x over previous
//
#include <hip/hip_runtime.h>

#define NQ 4
#define NL 2
#define NA 16
#define HDIM 256
#define BLK 64    // threads per block = 1 wave
#define RPB 64    // rows per block -> 4096 blocks at B=262144

template<int PATTERN>
__device__ __forceinline__ float swz_add(float x) {
    return x + __int_as_float(__builtin_amdgcn_ds_swizzle(__float_as_int(x), PATTERN));
}

// Generic 1-qubit gate on qubit with mask M. u = {u00r,u00i,u01r,u01i,u10r,u10i,u11r,u11i}
template<int M>
__device__ __forceinline__ void apply_u(float* sr, float* si, const float* u) {
    const float u00r = u[0], u00i = u[1], u01r = u[2], u01i = u[3];
    const float u10r = u[4], u10i = u[5], u11r = u[6], u11i = u[7];
#pragma unroll
    for (int k = 0; k < 16; ++k) {
        if (k & M) continue;
        const int k1 = k | M;
        const float a0r = sr[k],  a0i = si[k];
        const float a1r = sr[k1], a1i = si[k1];
        sr[k]  = u00r*a0r - u00i*a0i + u01r*a1r - u01i*a1i;
        si[k]  = u00r*a0i + u00i*a0r + u01r*a1i + u01i*a1r;
        sr[k1] = u10r*a0r - u10i*a0i + u11r*a1r - u11i*a1i;
        si[k1] = u10r*a0i + u10i*a0r + u11r*a1i + u11i*a1r;
    }
}

template<int MC, int MT>
__device__ __forceinline__ void cnot(float* sr, float* si) {
#pragma unroll
    for (int k = 0; k < 16; ++k) {
        if ((k & MC) && !(k & MT)) {
            const int k1 = k | MT;
            float tr = sr[k]; sr[k] = sr[k1]; sr[k1] = tr;
            float ti = si[k]; si[k] = si[k1]; si[k1] = ti;
        }
    }
}

__global__ __launch_bounds__(BLK) void qph_kernel(
    const float* __restrict__ h,
    const float* __restrict__ W_embed,
    const float* __restrict__ b_embed,
    const float* __restrict__ q_weights,
    const float* __restrict__ W_out,
    const float* __restrict__ b_out,
    float* __restrict__ out,
    int B)
{
    __shared__ __align__(16) float w_lds[NQ * HDIM];   // 4 KB  W_embed
    __shared__ float rot_lds[NL * NQ][8];              // Rot matrices (shared across batch)
    __shared__ float wout_lds[NA * NQ];
    __shared__ float bout_lds[NA];

    const int tid = threadIdx.x;
    const long rowBase = (long)blockIdx.x * RPB;

    // ---- stage shared weights ----
#pragma unroll
    for (int k = 0; k < 16; ++k) w_lds[tid + k * BLK] = W_embed[tid + k * BLK];
    if (tid < NA * NQ) wout_lds[tid] = W_out[tid];
    if (tid < NA)      bout_lds[tid] = b_out[tid];
    if (tid < NL * NQ) {
        // Rot(phi,theta,omega) = RZ(omega) RY(theta) RZ(phi)
        const float phi = q_weights[tid * 3 + 0];
        const float th  = q_weights[tid * 3 + 1];
        const float om  = q_weights[tid * 3 + 2];
        const float c  = cosf(0.5f * th), s  = sinf(0.5f * th);
        const float al = 0.5f * (phi + om), be = 0.5f * (phi - om);
        const float ca = cosf(al), sa = sinf(al);
        const float cb = cosf(be), sb = sinf(be);
        rot_lds[tid][0] =  ca * c;  rot_lds[tid][1] = -sa * c;   // u00
        rot_lds[tid][2] = -cb * s;  rot_lds[tid][3] = -sb * s;   // u01
        rot_lds[tid][4] =  cb * s;  rot_lds[tid][5] = -sb * s;   // u10
        rot_lds[tid][6] =  ca * c;  rot_lds[tid][7] =  sa * c;   // u11
    }
    __syncthreads();

    // ---- phase 1: angles = h @ W_embed^T, j OUTER so W regs persist across rows ----
    const int t = tid & 3;   // lane within 4-lane group
    const int g = tid >> 2;  // group id 0..15; group owns rows r0..r0+3
    const float be0 = b_embed[0], be1 = b_embed[1], be2 = b_embed[2], be3 = b_embed[3];

    // clamped row indices (in-bounds loads; OOB rows produce garbage that is
    // never stored)
    long r0 = rowBase + g * 4 + 0; if (r0 >= B) r0 = B - 1;
    long r1 = rowBase + g * 4 + 1; if (r1 >= B) r1 = B - 1;
    long r2 = rowBase + g * 4 + 2; if (r2 >= B) r2 = B - 1;
    long r3 = rowBase + g * 4 + 3; if (r3 >= B) r3 = B - 1;
    const float4* __restrict__ h4 = (const float4*)h;
    const long b0 = r0 * 64, b1 = r1 * 64, b2 = r2 * 64, b3 = r3 * 64;

    float acc[4][4];   // acc[row][q]
#pragma unroll
    for (int rr = 0; rr < 4; ++rr)
#pragma unroll
        for (int q = 0; q < 4; ++q) acc[rr][q] = 0.f;

#pragma unroll
    for (int j = 0; j < 16; ++j) {
        const int col = j * 16 + t * 4;
        const float4 w0 = *(const float4*)&w_lds[0 * HDIM + col];
        const float4 w1 = *(const float4*)&w_lds[1 * HDIM + col];
        const float4 w2 = *(const float4*)&w_lds[2 * HDIM + col];
        const float4 w3 = *(const float4*)&w_lds[3 * HDIM + col];
        const float4 h0 = h4[b0 + j * 4 + t];
        const float4 h1 = h4[b1 + j * 4 + t];
        const float4 h2 = h4[b2 + j * 4 + t];
        const float4 h3 = h4[b3 + j * 4 + t];
#define ACCUM(RR, HV) \
        acc[RR][0] = fmaf(HV.x, w0.x, fmaf(HV.y, w0.y, fmaf(HV.z, w0.z, fmaf(HV.w, w0.w, acc[RR][0])))); \
        acc[RR][1] = fmaf(HV.x, w1.x, fmaf(HV.y, w1.y, fmaf(HV.z, w1.z, fmaf(HV.w, w1.w, acc[RR][1])))); \
        acc[RR][2] = fmaf(HV.x, w2.x, fmaf(HV.y, w2.y, fmaf(HV.z, w2.z, fmaf(HV.w, w2.w, acc[RR][2])))); \
        acc[RR][3] = fmaf(HV.x, w3.x, fmaf(HV.y, w3.y, fmaf(HV.z, w3.z, fmaf(HV.w, w3.w, acc[RR][3]))))
        ACCUM(0, h0);
        ACCUM(1, h1);
        ACCUM(2, h2);
        ACCUM(3, h3);
#undef ACCUM
    }

    // 4-lane butterfly per row; lane t keeps row rr==t -> thread owns row rowBase+tid
    float my0 = 0.f, my1 = 0.f, my2 = 0.f, my3 = 0.f;
#pragma unroll
    for (int rr = 0; rr < 4; ++rr) {
        float v0 = acc[rr][0], v1 = acc[rr][1], v2 = acc[rr][2], v3 = acc[rr][3];
        v0 = swz_add<0x041F>(v0); v0 = swz_add<0x081F>(v0);
        v1 = swz_add<0x041F>(v1); v1 = swz_add<0x081F>(v1);
        v2 = swz_add<0x041F>(v2); v2 = swz_add<0x081F>(v2);
        v3 = swz_add<0x041F>(v3); v3 = swz_add<0x081F>(v3);
        if (t == rr) { my0 = v0; my1 = v1; my2 = v2; my3 = v3; }
    }

    // ---- phase 2: this thread owns row rowBase + tid ----
    const long grow = rowBase + tid;
    if (grow >= B) return;

    const float angs[4] = {tanhf(my0 + be0), tanhf(my1 + be1),
                           tanhf(my2 + be2), tanhf(my3 + be3)};

    float sr[16], si[16];
#pragma unroll
    for (int k = 0; k < 16; ++k) { sr[k] = 0.f; si[k] = 0.f; }
    sr[0] = 1.0f;

    // AngleEmbedding: RX(theta_q) on qubit q
#pragma unroll
    for (int q = 0; q < NQ; ++q) {
        const float th = angs[q];
        const float c = __cosf(0.5f * th), s = __sinf(0.5f * th);
        const int m = 8 >> q;
#pragma unroll
        for (int k = 0; k < 16; ++k) {
            if (k & m) continue;
            const int k1 = k | m;
            const float a0r = sr[k],  a0i = si[k];
            const float a1r = sr[k1], a1i = si[k1];
            sr[k]  = c * a0r + s * a1i;
            si[k]  = c * a0i - s * a1r;
            sr[k1] = s * a0i + c * a1r;
            si[k1] = c * a1i - s * a0r;
        }
    }

    // StronglyEntanglingLayers
    apply_u<8>(sr, si, rot_lds[0]);
    apply_u<4>(sr, si, rot_lds[1]);
    apply_u<2>(sr, si, rot_lds[2]);
    apply_u<1>(sr, si, rot_lds[3]);
    cnot<8, 4>(sr, si);
    cnot<4, 2>(sr, si);
    cnot<2, 1>(sr, si);
    cnot<1, 8>(sr, si);
    apply_u<8>(sr, si, rot_lds[4]);
    apply_u<4>(sr, si, rot_lds[5]);
    apply_u<2>(sr, si, rot_lds[6]);
    apply_u<1>(sr, si, rot_lds[7]);
    cnot<8, 2>(sr, si);
    cnot<4, 1>(sr, si);
    cnot<2, 8>(sr, si);
    cnot<1, 4>(sr, si);

    // PauliZ expectations
    float p[16];
#pragma unroll
    for (int k = 0; k < 16; ++k) p[k] = sr[k] * sr[k] + si[k] * si[k];
    float z[4];
#pragma unroll
    for (int q = 0; q < NQ; ++q) {
        const int m = 8 >> q;
        float zz = 0.f;
#pragma unroll
        for (int k = 0; k < 16; ++k) zz += (k & m) ? -p[k] : p[k];
        z[q] = zz;
    }

    // out = z @ W_out^T + b_out
    float4* out4 = (float4*)(out + grow * (long)NA);
#pragma unroll
    for (int i = 0; i < 4; ++i) {
        float o[4];
#pragma unroll
        for (int jj = 0; jj < 4; ++jj) {
            const int a = i * 4 + jj;
            float v = bout_lds[a];
#pragma unroll
            for (int q = 0; q < NQ; ++q) v = fmaf(z[q], wout_lds[a * 4 + q], v);
            o[jj] = v;
        }
        out4[i] = make_float4(o[0], o[1], o[2], o[3]);
    }
}

extern "C" void kernel_launch(void* const* d_in, const int* in_sizes, int n_in,
                              void* d_out, int out_size, void* d_ws, size_t ws_size,
                              hipStream_t stream) {
    const float* h         = (const float*)d_in[0];
    const float* W_embed   = (const float*)d_in[1];
    const float* b_embed   = (const float*)d_in[2];
    const float* q_weights = (const float*)d_in[3];
    const float* W_out     = (const float*)d_in[4];
    const float* b_out     = (const float*)d_in[5];
    float* out = (float*)d_out;

    const int B = in_sizes[0] / HDIM;
    const int blocks = (B + RPB - 1) / RPB;
    qph_kernel<<<blocks, BLK, 0, stream>>>(h, W_embed, b_embed, q_weights, W_out, b_out, out, B);
}